// Round 8
// baseline (519.026 us; speedup 1.0000x reference)
//
#include <hip/hip_runtime.h>

// Problem constants (from reference): z (64,128,64,64) f32, emb (256,128) f32
#define K_EMB   256
#define C_DIM   128
#define HW      4096            // 64*64
#define NPOS    262144          // 64*HW
#define Q_ELEMS 33554432        // 64*128*64*64
#define IDX_OFF Q_ELEMS         // idx chunk offset in d_out (floats)
#define LOSS_OFF (Q_ELEMS + NPOS)

#define BLKP 64                 // positions per block (z tile = 128c x 64p = 32 KB LDS)
#define TK   32                 // codes per wave (k-octant)
#define NQ   8                  // k-octants = waves per block
#define NTHR 512                // 8 waves
#define CC   32                 // c-chunk size for emb staging (32c x 256k = 32 KB)
#define NCHUNK (C_DIM / CC)     // 4

// ws layout (floats): [0,256) enorm, [256] loss accumulator, [512, 512+32768) embT (c*256+k)
#define WS_ENORM 0
#define WS_ACC   256
#define WS_EMBT  512
#define WS_NEED_FULL  ((WS_EMBT + C_DIM * K_EMB) * 4)

// ---------------------------------------------------------------------------
// Kernel A: parallel emb transpose (one block per c), zero loss accum.
// ---------------------------------------------------------------------------
__global__ __launch_bounds__(K_EMB) void vq_transpose(const float* __restrict__ emb,
                                                      float* __restrict__ ws,
                                                      int use_embT) {
    const int c = blockIdx.x, k = threadIdx.x;
    if (use_embT) ws[WS_EMBT + c * K_EMB + k] = emb[k * C_DIM + c];
    if (c == 0 && k == 0) ws[WS_ACC] = 0.f;
}

// ---------------------------------------------------------------------------
// Kernel B: per-code squared norms. Same ascending-c serial fmaf chain as the
// absmax-0 kernels (float4 components consumed in x,y,z,w = ascending c).
// ---------------------------------------------------------------------------
__global__ __launch_bounds__(K_EMB) void vq_enorm(const float* __restrict__ emb,
                                                  float* __restrict__ ws) {
    const int k = threadIdx.x;
    const float4* __restrict__ er = reinterpret_cast<const float4*>(emb + k * C_DIM);
    float s = 0.f;
    #pragma unroll
    for (int j = 0; j < C_DIM / 4; ++j) {
        float4 v = er[j];
        s = fmaf(v.x, v.x, s);
        s = fmaf(v.y, v.y, s);
        s = fmaf(v.z, v.z, s);
        s = fmaf(v.w, v.w, s);
    }
    ws[WS_ENORM + k] = s;
}

// ---------------------------------------------------------------------------
// Kernel 1: ALL-DS 8-way split-K VALU GEMM + argmin.
//
// R12 (this round): three falsified operand paths for emb --
//   SMEM  (R4/R6): retires OUT-OF-ORDER on lgkmcnt -> compiler must drain
//          lgkmcnt(0) every c-step; per-wave duty pinned ~18%, busy 55-59%.
//   L1/VMEM (R7): per-lane loads duplicate each embT line 16x across
//          position-groups -> L1 BW (16KB/c-step vs 1KB unique) caps duty
//          ~11%; busy 52%.
// The operand pipe must be counted-in-order AND broadcast-capable: LDS.
// Stage embT into LDS in 4 c-chunks ([32c][256k] = 32 KB, single-buffered,
// T14 reg-prefetch: next chunk -> 16 VGPRs under current chunk's ~2000cyc
// compute; only ds_write+barrier exposed). Inner loop: 1 ds_read_b32 (z)
// + 8 ds_read_b128 (emb, wave-uniform addr = broadcast, conflict-free) +
// 33 fmaf -- zero SMEM, zero VMEM. LDS 68 KB -> 2 blocks/CU = 4 waves/SIMD,
// duty ceiling ~85% -> VALU saturates. LDS BW demand ~24 B/cyc << 256.
//
// Numerics: bit-identical to the absmax-0 lineage. embc is a bit-copy;
// chunks ascend c so every acc[j]/znorm chain is the same serial
// ascending-c fmaf order; d = (znorm - 2*acc) + enorm[k]; strict <
// ascending-k within octant, ascending-octant combine = global first-min.
// Loss epilogue byte-for-byte R6 (same 4096 partial groups, shfl tree,
// atomic count).
// ---------------------------------------------------------------------------
template <int UT>
__global__ __launch_bounds__(NTHR, 4) void vq_main(const float* __restrict__ z,
                                                   const float* __restrict__ emb,
                                                   const float* __restrict__ ws,
                                                   float* __restrict__ out,
                                                   float* __restrict__ loss_acc) {
    __shared__ float zlds[C_DIM * BLKP];     // [c][p], 32 KB
    __shared__ float embc[CC * K_EMB];       // emb c-chunk [cc][k], 32 KB
    __shared__ float sh_best[NQ * BLKP];     // 2 KB
    __shared__ int   sh_bidx[NQ * BLKP];     // 2 KB

    const int t    = threadIdx.x;
    const int lane = t & 63;                   // position within block
    const int kq   = t >> 6;                   // wave id = k-octant
    const int blk  = blockIdx.x;
    const int b    = blk >> 6;                 // 4096/64 = 64 blocks per image
    const int hw0  = (blk & 63) * BLKP;
    const size_t zoff = (size_t)b * (C_DIM * HW) + hw0;
    const float* __restrict__ zsrc = z + zoff;

    const float* __restrict__ embT  = ws + WS_EMBT;
    const float* __restrict__ enorm = ws + WS_ENORM;

    // ---- Stage z tile (coalesced float4, [c][p]) + emb chunk 0 ----
    {
        const float4* __restrict__ zs4 = reinterpret_cast<const float4*>(zsrc);
        float4* __restrict__ zl4 = reinterpret_cast<float4*>(zlds);
        #pragma unroll
        for (int j = 0; j < (C_DIM * BLKP / 4) / NTHR; ++j) {   // 4 iters
            const int i4 = t + j * NTHR;
            const int c  = i4 >> 4;            // 16 float4 per c-row (64 floats)
            const int p4 = i4 & 15;
            zl4[i4] = zs4[(size_t)c * (HW / 4) + p4];
        }
        if (UT) {
            const float4* __restrict__ es4 = reinterpret_cast<const float4*>(embT);
            float4* __restrict__ el4 = reinterpret_cast<float4*>(embc);
            #pragma unroll
            for (int i = 0; i < 4; ++i)        // 2048 float4 per chunk
                el4[t + i * NTHR] = es4[t + i * NTHR];
        }
    }
    __syncthreads();

    // kq is uniform across each 64-lane wave: pin k-base in an SGPR
    // (R6 lesson, R7 fix) -- here it keeps the embc read addr SGPR-based.
    const int kbase = __builtin_amdgcn_readfirstlane(kq * TK);

    float acc[TK];
    #pragma unroll
    for (int j = 0; j < TK; ++j) acc[j] = 0.f;
    float znorm = 0.f;

    if (UT) {
        float4 pf[4];
        #pragma unroll
        for (int ch = 0; ch < NCHUNK; ++ch) {
            // T14 prefetch: next chunk global->regs, hidden under compute.
            if (ch + 1 < NCHUNK) {
                const float4* __restrict__ ns4 =
                    reinterpret_cast<const float4*>(embT + (ch + 1) * CC * K_EMB);
                #pragma unroll
                for (int i = 0; i < 4; ++i) pf[i] = ns4[t + i * NTHR];
            }
            // ---- all-DS inner loop: 1 ds_b32 + 8 ds_b128 + 33 fmaf ----
            #pragma unroll 2
            for (int c = 0; c < CC; ++c) {
                const int cg = ch * CC + c;                  // global c (ascending)
                const float zc = zlds[cg * BLKP + lane];     // 2-way alias = free
                znorm = fmaf(zc, zc, znorm);                 // same serial chain
                const float4* __restrict__ ep4 =
                    reinterpret_cast<const float4*>(&embc[c * K_EMB + kbase]);
                #pragma unroll
                for (int j4 = 0; j4 < TK / 4; ++j4) {
                    const float4 e = ep4[j4];                // broadcast ds_read_b128
                    acc[j4 * 4 + 0] = fmaf(zc, e.x, acc[j4 * 4 + 0]);
                    acc[j4 * 4 + 1] = fmaf(zc, e.y, acc[j4 * 4 + 1]);
                    acc[j4 * 4 + 2] = fmaf(zc, e.z, acc[j4 * 4 + 2]);
                    acc[j4 * 4 + 3] = fmaf(zc, e.w, acc[j4 * 4 + 3]);
                }
            }
            if (ch + 1 < NCHUNK) {
                __syncthreads();   // all octants done READING chunk ch
                float4* __restrict__ el4 = reinterpret_cast<float4*>(embc);
                #pragma unroll
                for (int i = 0; i < 4; ++i) el4[t + i * NTHR] = pf[i];
                __syncthreads();   // chunk ch+1 visible
            }
        }
    } else {
        // Fallback (no ws room for embT): R6's direct-global path.
        #pragma unroll 2
        for (int c = 0; c < C_DIM; ++c) {
            const float zc = zlds[c * BLKP + lane];
            znorm = fmaf(zc, zc, znorm);
            #pragma unroll
            for (int j = 0; j < TK; ++j)
                acc[j] = fmaf(zc, emb[(kbase + j) * C_DIM + c], acc[j]);
        }
    }

    float best = 3.402823466e38f;
    int   bidx = 0;
    #pragma unroll
    for (int j = 0; j < TK; ++j) {
        const float d = (znorm - 2.0f * acc[j]) + enorm[kbase + j];
        if (d < best) { best = d; bidx = kbase + j; }   // strict < = first-min
    }

    sh_best[t] = best;   // t == kq*BLKP + lane
    sh_bidx[t] = bidx;
    __syncthreads();

    if (t < BLKP) {   // wave 0: thread t owns position p = t
        const int p = t;
        float bb = sh_best[p];
        int   bi = sh_bidx[p];
        #pragma unroll
        for (int q = 1; q < NQ; ++q) {
            const float bq = sh_best[q * BLKP + p];
            const int   iq = sh_bidx[q * BLKP + p];
            if (bq < bb) { bb = bq; bi = iq; }  // strict <: lower octant wins ties
        }
        const int fin = bi;
        const int pos = blk * BLKP + p;
        __builtin_nontemporal_store((float)fin, &out[IDX_OFF + pos]);

        // Epilogue: q = z + (e - z), loss += (e - z)^2. z from LDS (bit-copy),
        // e from row-major emb via float4 (bit-equal to embT), ascending-c
        // 128-term chain identical to the absmax-0 lineage.
        float lsum = 0.f;
        float* qp = out + zoff + p;
        const float4* __restrict__ er =
            reinterpret_cast<const float4*>(emb + fin * C_DIM);
        #pragma unroll 4
        for (int j = 0; j < C_DIM / 4; ++j) {
            const float4 ev = er[j];
            const int c0 = j * 4;
            const float z0 = zlds[(c0 + 0) * BLKP + p];
            const float z1 = zlds[(c0 + 1) * BLKP + p];
            const float z2 = zlds[(c0 + 2) * BLKP + p];
            const float z3 = zlds[(c0 + 3) * BLKP + p];
            const float d0 = ev.x - z0, d1 = ev.y - z1;
            const float d2 = ev.z - z2, d3 = ev.w - z3;
            lsum = fmaf(d0, d0, lsum);
            lsum = fmaf(d1, d1, lsum);
            lsum = fmaf(d2, d2, lsum);
            lsum = fmaf(d3, d3, lsum);
            __builtin_nontemporal_store(z0 + d0, &qp[(size_t)(c0 + 0) * HW]);
            __builtin_nontemporal_store(z1 + d1, &qp[(size_t)(c0 + 1) * HW]);
            __builtin_nontemporal_store(z2 + d2, &qp[(size_t)(c0 + 2) * HW]);
            __builtin_nontemporal_store(z3 + d3, &qp[(size_t)(c0 + 3) * HW]);
        }

        // Wave-level reduction, one atomic per block (same 4096 partials).
        #pragma unroll
        for (int off = 32; off > 0; off >>= 1)
            lsum += __shfl_down(lsum, off, 64);
        if (p == 0) atomicAdd(loss_acc, lsum);
    }
}

// ---------------------------------------------------------------------------
// Kernel 2: finalize the two scalar losses.
// ---------------------------------------------------------------------------
__global__ void vq_finalize(const float* __restrict__ loss_acc,
                            float* __restrict__ out_losses) {
    float S = loss_acc[0];
    float mean = S / (float)Q_ELEMS;
    out_losses[0] = 0.25f * mean;  // commitment_loss
    out_losses[1] = mean;          // codebook_loss
}

extern "C" void kernel_launch(void* const* d_in, const int* in_sizes, int n_in,
                              void* d_out, int out_size, void* d_ws, size_t ws_size,
                              hipStream_t stream) {
    const float* z   = (const float*)d_in[0];
    const float* emb = (const float*)d_in[1];
    float* out = (float*)d_out;
    float* ws  = (float*)d_ws;

    int use_embT = (ws_size >= (size_t)WS_NEED_FULL) ? 1 : 0;

    vq_transpose<<<C_DIM, K_EMB, 0, stream>>>(emb, ws, use_embT);
    vq_enorm<<<1, K_EMB, 0, stream>>>(emb, ws);
    if (use_embT)
        vq_main<1><<<NPOS / BLKP, NTHR, 0, stream>>>(z, emb, ws, out, ws + WS_ACC);
    else
        vq_main<0><<<NPOS / BLKP, NTHR, 0, stream>>>(z, emb, ws, out, ws + WS_ACC);
    vq_finalize<<<1, 1, 0, stream>>>(ws + WS_ACC, out + LOSS_OFF);
}

// Round 10
// 412.204 us; speedup vs baseline: 1.2591x; 1.2591x over previous
//
#include <hip/hip_runtime.h>

// Problem constants (from reference): z (64,128,64,64) f32, emb (256,128) f32
#define K_EMB   256
#define C_DIM   128
#define HW      4096            // 64*64
#define NPOS    262144          // 64*HW
#define Q_ELEMS 33554432        // 64*128*64*64
#define IDX_OFF Q_ELEMS         // idx chunk offset in d_out (floats)
#define LOSS_OFF (Q_ELEMS + NPOS)

#define BLKP 64                 // positions per block (z tile = 128c x 64p = 32 KB LDS)
#define NTHR 512                // 8 waves
#define NW   8
#define CC   16                 // c per emb chunk (16c x 256k = 16 KB)
#define NCHUNK (C_DIM / CC)     // 8
#define TM   4                  // positions per thread
#define TN   8                  // codes per thread
#define NG   32                 // combine groups (8 waves x 4 cg), group g owns k [8g,8g+8)

// ws layout (floats): [0,256) enorm, [256] loss accumulator, [512, 512+32768) embT (c*256+k)
#define WS_ENORM 0
#define WS_ACC   256
#define WS_EMBT  512
#define WS_NEED_FULL  ((WS_EMBT + C_DIM * K_EMB) * 4)

// Async global->LDS, 16 B per lane. Dest is wave-uniform base + lane*16 (m104):
// all our dest indices are t*16B + const, i.e. exactly base + lane*16 per wave.
#define GLOAD16(gsrc, ldst) __builtin_amdgcn_global_load_lds(                 \
    (const __attribute__((address_space(1))) void*)(gsrc),                    \
    (__attribute__((address_space(3))) void*)(ldst), 16, 0, 0)

// ---------------------------------------------------------------------------
// Kernel A: parallel emb transpose (one block per c) + enorm (block C_DIM).
// enorm: same ascending-c serial fmaf chain as the absmax-0 lineage (float4
// components consumed x,y,z,w = ascending c).
// ---------------------------------------------------------------------------
__global__ __launch_bounds__(K_EMB) void vq_prep(const float* __restrict__ emb,
                                                 float* __restrict__ ws,
                                                 int use_embT) {
    const int c = blockIdx.x, k = threadIdx.x;
    if (c < C_DIM) {
        if (use_embT) ws[WS_EMBT + c * K_EMB + k] = emb[k * C_DIM + c];
        if (c == 0 && k == 0) ws[WS_ACC] = 0.f;
    } else {
        const float4* __restrict__ er = reinterpret_cast<const float4*>(emb + k * C_DIM);
        float s = 0.f;
        #pragma unroll
        for (int j = 0; j < C_DIM / 4; ++j) {
            float4 v = er[j];
            s = fmaf(v.x, v.x, s);
            s = fmaf(v.y, v.y, s);
            s = fmaf(v.z, v.z, s);
            s = fmaf(v.w, v.w, s);
        }
        ws[WS_ENORM + k] = s;
    }
}

// ---------------------------------------------------------------------------
// Kernel 1: square register-tile (4 pos x 8 codes) VALU GEMM + argmin.
//
// R14 = R13 resubmission (bench infra failed twice; audit found no hang
// candidate: gload_lds dests are wave-uniform-base+lane*16, double-buffer
// sealed by __syncthreads' vmcnt(0)+lgkmcnt(0) drain, no divergent
// barriers, no OOB). Operand-path study:
//   SMEM (R4/R6): s_load retires out-of-order -> lgkmcnt(0) drain per
//     c-step, duty pinned ~18%, busy ceiling 59%.
//   VMEM per-lane (R7): 16x L1 line duplication -> duty ~11%.
//   LDS + register prefetch (R8): pf[16 VGPR] + acc[32] spilled ->
//     WRITE_SIZE 132->401 MB (scratch), duty ~12%.
// Fix combines the lessons: both operands from LDS on counted in-order
// lgkmcnt; staging via global_load_lds width=16 (ZERO staging VGPRs,
// counted on vmcnt); square 4x8 thread tile cuts LDS instrs to 3
// ds_read_b128 per 36 fmaf (fma/ds = 10.7, all reads bank-conflict-free
// by construction). emb double-buffered in 16 KB c-chunks: loads issued at
// chunk start, one barrier-drain per ~1150-cyc chunk (embT is L2-hot,
// ~200 cyc) -> hidden. LDS 75 KB -> 2 blocks/CU = 4 waves/SIMD.
//
// Numerics: bit-identical to the absmax-0 lineage. Every (pos,code) dot and
// every znorm is the same serial ascending-c fmaf chain (znorm in-loop,
// redundant across (cg,wave) -- same bits from same LDS data, +12.5%
// FLOPs); d = (znorm - 2*acc) + enorm[k] exactly; thread scans its 8 codes
// ascending k with strict <, groups combined ascending g (kbase = 8g) with
// strict < = global first-min. Loss epilogue byte-for-byte R6: wave-0
// lanes own positions blk*64+0..63, same 128-term ascending-c chains, same
// shfl tree, same 4096 atomics.
// ---------------------------------------------------------------------------
template <int UT>
__global__ __launch_bounds__(NTHR, 4) void vq_main(const float* __restrict__ z,
                                                   const float* __restrict__ emb,
                                                   const float* __restrict__ ws,
                                                   float* __restrict__ out,
                                                   float* __restrict__ loss_acc) {
    __shared__ float zlds[C_DIM * BLKP];        // [c][p], 32 KB
    __shared__ float ebuf[2][CC * K_EMB];       // emb chunk double-buffer, 2 x 16 KB
    __shared__ float shen[K_EMB];               // enorm bit-copy, 1 KB
    __shared__ float shpb[NG * BLKP];           // partial bests, 8 KB
    __shared__ unsigned int shpi[NG * BLKP / 4];// packed u8 indices, 2 KB

    const int t    = threadIdx.x;
    const int lane = t & 63;
    const int w    = t >> 6;                   // wave id
    const int pg   = lane & 15;                // position group (16 per wave)
    const int cg   = lane >> 4;                // code group (4 per wave)
    const int p0   = pg * 4;                   // 4 positions per thread
    const int k0   = w * 32 + cg * 8;          // 8 codes per thread
    const int blk  = blockIdx.x;
    const int b    = blk >> 6;                 // 64 blocks per image
    const int hw0  = (blk & 63) * BLKP;
    const size_t zoff = (size_t)b * (C_DIM * HW) + hw0;
    const float* __restrict__ zsrc = z + zoff;

    const float* __restrict__ embT    = ws + WS_EMBT;
    const float* __restrict__ enorm_g = ws + WS_ENORM;

    // ---- Prologue staging: z tile (32 KB) + emb chunk 0, all via gload_lds.
    // dest index = t*16B + const  ==  wave-uniform base + lane*16  (valid).
    #pragma unroll
    for (int j = 0; j < 4; ++j) {
        const int i4 = t + j * NTHR;           // float4 index into [c][p]
        const int c  = i4 >> 4;                // 16 float4 per c-row
        const int p4 = i4 & 15;
        GLOAD16(zsrc + (size_t)c * HW + p4 * 4, &zlds[i4 * 4]);
    }
    if (UT) {
        #pragma unroll
        for (int s = 0; s < 2; ++s) {
            const int i4 = t + s * NTHR;
            GLOAD16(embT + i4 * 4, &ebuf[0][i4 * 4]);
        }
    }
    if (t < K_EMB) shen[t] = enorm_g[t];       // bit-copy
    __syncthreads();                            // drains vmcnt(0) + lgkmcnt(0)

    float acc[TM][TN];
    float zn[TM];
    #pragma unroll
    for (int i = 0; i < TM; ++i) {
        zn[i] = 0.f;
        #pragma unroll
        for (int j = 0; j < TN; ++j) acc[i][j] = 0.f;
    }

    if (UT) {
        for (int ch = 0; ch < NCHUNK; ++ch) {
            // Issue next chunk's loads first (zero VGPRs, counted on vmcnt).
            // Overwrite of ebuf[(ch+1)&1] is safe: last read was chunk ch-1,
            // sealed by the barrier at end of ch-1.
            if (ch + 1 < NCHUNK) {
                const float* __restrict__ src = embT + (ch + 1) * CC * K_EMB;
                #pragma unroll
                for (int s = 0; s < 2; ++s) {
                    const int i4 = t + s * NTHR;
                    GLOAD16(src + i4 * 4, &ebuf[(ch + 1) & 1][i4 * 4]);
                }
            }
            const float* __restrict__ eb = ebuf[ch & 1];
            const int cbase = ch * CC;
            // 3 ds_read_b128 + 36 fmaf per c-step; conflict-free by layout:
            //  z: 16 addrs (pg*16B), 4-lane broadcast, 2-way bank alias = free
            //  e: 4 addrs (cg*32B), 16-lane broadcast, bank-quads disjoint
            #pragma unroll 4
            for (int c = 0; c < CC; ++c) {
                const float4 zv = *reinterpret_cast<const float4*>(
                    &zlds[(cbase + c) * BLKP + p0]);
                const float4 e0 = *reinterpret_cast<const float4*>(
                    &eb[c * K_EMB + k0]);
                const float4 e1 = *reinterpret_cast<const float4*>(
                    &eb[c * K_EMB + k0 + 4]);
                const float zz[TM] = {zv.x, zv.y, zv.z, zv.w};
                const float ee[TN] = {e0.x, e0.y, e0.z, e0.w,
                                      e1.x, e1.y, e1.z, e1.w};
                #pragma unroll
                for (int i = 0; i < TM; ++i) {
                    zn[i] = fmaf(zz[i], zz[i], zn[i]);   // serial asc-c chain
                    #pragma unroll
                    for (int j = 0; j < TN; ++j)
                        acc[i][j] = fmaf(zz[i], ee[j], acc[i][j]);
                }
            }
            if (ch + 1 < NCHUNK) {
                __syncthreads();   // drains vmcnt(0): chunk ch+1 visible,
                                   // ebuf[ch&1] released for next overwrite
            }
        }
    } else {
        // Fallback (no ws room for embT): direct global emb, correct but slow.
        #pragma unroll 2
        for (int c = 0; c < C_DIM; ++c) {
            const float4 zv = *reinterpret_cast<const float4*>(&zlds[c * BLKP + p0]);
            const float zz[TM] = {zv.x, zv.y, zv.z, zv.w};
            float ee[TN];
            #pragma unroll
            for (int j = 0; j < TN; ++j) ee[j] = emb[(k0 + j) * C_DIM + c];
            #pragma unroll
            for (int i = 0; i < TM; ++i) {
                zn[i] = fmaf(zz[i], zz[i], zn[i]);
                #pragma unroll
                for (int j = 0; j < TN; ++j)
                    acc[i][j] = fmaf(zz[i], ee[j], acc[i][j]);
            }
        }
    }

    // ---- Thread-local argmin over its 8 codes (ascending k, strict <) ----
    {
        float pb[TM];
        int   pi_[TM];
        #pragma unroll
        for (int i = 0; i < TM; ++i) {
            float best = 3.402823466e38f;
            int   bi = 0;
            #pragma unroll
            for (int j = 0; j < TN; ++j) {
                const float d = (zn[i] - 2.0f * acc[i][j]) + shen[k0 + j];
                if (d < best) { best = d; bi = k0 + j; }   // strict < = first-min
            }
            pb[i] = best; pi_[i] = bi;
        }
        const int g = w * 4 + cg;              // ascending g <=> ascending kbase
        *reinterpret_cast<float4*>(&shpb[g * BLKP + p0]) =
            make_float4(pb[0], pb[1], pb[2], pb[3]);
        shpi[g * 16 + pg] = (unsigned)(pi_[0] & 255)
                          | ((unsigned)(pi_[1] & 255) << 8)
                          | ((unsigned)(pi_[2] & 255) << 16)
                          | ((unsigned)(pi_[3] & 255) << 24);
    }
    __syncthreads();

    if (t < BLKP) {   // wave 0: thread t owns position p = t
        const int p = t;
        float bb = shpb[p];
        int   bi = (int)((shpi[p >> 2] >> ((p & 3) * 8)) & 255u);
        #pragma unroll 4
        for (int g = 1; g < NG; ++g) {
            const float bq = shpb[g * BLKP + p];
            if (bq < bb) {                     // strict <: lower k-group wins ties
                bb = bq;
                bi = (int)((shpi[g * 16 + (p >> 2)] >> ((p & 3) * 8)) & 255u);
            }
        }
        const int fin = bi;
        const int pos = blk * BLKP + p;
        __builtin_nontemporal_store((float)fin, &out[IDX_OFF + pos]);

        // Epilogue: q = z + (e - z), loss += (e - z)^2. z from LDS (bit-copy),
        // e from row-major emb via float4 (bit-equal to embT), ascending-c
        // 128-term chain identical to the absmax-0 lineage.
        float lsum = 0.f;
        float* qp = out + zoff + p;
        const float4* __restrict__ er =
            reinterpret_cast<const float4*>(emb + fin * C_DIM);
        #pragma unroll 4
        for (int j = 0; j < C_DIM / 4; ++j) {
            const float4 ev = er[j];
            const int c0 = j * 4;
            const float z0 = zlds[(c0 + 0) * BLKP + p];
            const float z1 = zlds[(c0 + 1) * BLKP + p];
            const float z2 = zlds[(c0 + 2) * BLKP + p];
            const float z3 = zlds[(c0 + 3) * BLKP + p];
            const float d0 = ev.x - z0, d1 = ev.y - z1;
            const float d2 = ev.z - z2, d3 = ev.w - z3;
            lsum = fmaf(d0, d0, lsum);
            lsum = fmaf(d1, d1, lsum);
            lsum = fmaf(d2, d2, lsum);
            lsum = fmaf(d3, d3, lsum);
            __builtin_nontemporal_store(z0 + d0, &qp[(size_t)(c0 + 0) * HW]);
            __builtin_nontemporal_store(z1 + d1, &qp[(size_t)(c0 + 1) * HW]);
            __builtin_nontemporal_store(z2 + d2, &qp[(size_t)(c0 + 2) * HW]);
            __builtin_nontemporal_store(z3 + d3, &qp[(size_t)(c0 + 3) * HW]);
        }

        // Wave-level reduction, one atomic per block (same 4096 partials).
        #pragma unroll
        for (int off = 32; off > 0; off >>= 1)
            lsum += __shfl_down(lsum, off, 64);
        if (p == 0) atomicAdd(loss_acc, lsum);
    }
}

// ---------------------------------------------------------------------------
// Kernel 2: finalize the two scalar losses.
// ---------------------------------------------------------------------------
__global__ void vq_finalize(const float* __restrict__ loss_acc,
                            float* __restrict__ out_losses) {
    float S = loss_acc[0];
    float mean = S / (float)Q_ELEMS;
    out_losses[0] = 0.25f * mean;  // commitment_loss
    out_losses[1] = mean;          // codebook_loss
}

extern "C" void kernel_launch(void* const* d_in, const int* in_sizes, int n_in,
                              void* d_out, int out_size, void* d_ws, size_t ws_size,
                              hipStream_t stream) {
    const float* z   = (const float*)d_in[0];
    const float* emb = (const float*)d_in[1];
    float* out = (float*)d_out;
    float* ws  = (float*)d_ws;

    int use_embT = (ws_size >= (size_t)WS_NEED_FULL) ? 1 : 0;

    vq_prep<<<C_DIM + 1, K_EMB, 0, stream>>>(emb, ws, use_embT);
    if (use_embT)
        vq_main<1><<<NPOS / BLKP, NTHR, 0, stream>>>(z, emb, ws, out, ws + WS_ACC);
    else
        vq_main<0><<<NPOS / BLKP, NTHR, 0, stream>>>(z, emb, ws, out, ws + WS_ACC);
    vq_finalize<<<1, 1, 0, stream>>>(ws + WS_ACC, out + LOSS_OFF);
}